// Round 12
// baseline (3028.380 us; speedup 1.0000x reference)
//
#include <hip/hip_runtime.h>
#include <stdint.h>

#define LANE ((int)(threadIdx.x & 63))
#define WID  ((int)(threadIdx.x >> 6))

__device__ __forceinline__ float exact_d2(float ax, float ay, float az,
                                          float bx, float by, float bz) {
  float dx = ax - bx, dy = ay - by, dz = az - bz;
  return __fadd_rn(__fadd_rn(__fmul_rn(dx, dx), __fmul_rn(dy, dy)), __fmul_rn(dz, dz));
}

__device__ __forceinline__ void lds_fence() {
  asm volatile("s_waitcnt lgkmcnt(0)" ::: "memory");
}

// Barrier that does NOT drain vmcnt: LDS-visibility fence + raw s_barrier.
__device__ __forceinline__ void lds_barrier() {
  asm volatile("s_waitcnt lgkmcnt(0)" ::: "memory");
  __builtin_amdgcn_s_barrier();
  asm volatile("" ::: "memory");
}

// Wave-wide max via DPP. ROW_SHR 1/2/4/8 accumulates row maxima into lanes
// 15/31/47/63; row_bcast15 (rows 1,3) then row_bcast31 (rows 2,3) fold rows;
// lane 63 holds the full wave max. (R7-verified.)
__device__ __forceinline__ float wave_max_dpp(float v) {
  const int NI = 0xff800000;  // -inf bits: identity
  int x = __float_as_int(v);
  x = __float_as_int(fmaxf(__int_as_float(x),
      __int_as_float(__builtin_amdgcn_update_dpp(NI, x, 0x111, 0xf, 0xf, false))));
  x = __float_as_int(fmaxf(__int_as_float(x),
      __int_as_float(__builtin_amdgcn_update_dpp(NI, x, 0x112, 0xf, 0xf, false))));
  x = __float_as_int(fmaxf(__int_as_float(x),
      __int_as_float(__builtin_amdgcn_update_dpp(NI, x, 0x114, 0xf, 0xf, false))));
  x = __float_as_int(fmaxf(__int_as_float(x),
      __int_as_float(__builtin_amdgcn_update_dpp(NI, x, 0x118, 0xf, 0xf, false))));
  x = __float_as_int(fmaxf(__int_as_float(x),
      __int_as_float(__builtin_amdgcn_update_dpp(NI, x, 0x142, 0xa, 0xf, false))));
  x = __float_as_int(fmaxf(__int_as_float(x),
      __int_as_float(__builtin_amdgcn_update_dpp(NI, x, 0x143, 0xc, 0xf, false))));
  return __int_as_float(__builtin_amdgcn_readlane(x, 63));
}

// ---------------- FPS body: symmetric waves, keys-only LDS round (R8/R10) --------
template <int NPTS, int NSAMP>
__device__ void fps_body(const float* __restrict__ coords, int b,
                         int* __restrict__ out_idx, float* __restrict__ out_pos,
                         char* smem_raw) {
  constexpr int PT = NPTS / 256;
  float* sx = (float*)smem_raw;                 // [NPTS]
  float* sy = sx + NPTS;                        // [NPTS]
  float* sz = sy + NPTS;                        // [NPTS]
  uint64_t* swk = (uint64_t*)(sz + NPTS);       // [2][4] keys
  const float* pos = coords + (size_t)b * NPTS * 3;
  const int tid = (int)threadIdx.x;
  const int lane = LANE, wid = WID;

  __builtin_amdgcn_s_setprio(3);  // FPS is the serial critical path

  float px[PT], py[PT], pz[PT], dd[PT];
  const int i0 = tid * PT;
#pragma unroll
  for (int k = 0; k < PT; ++k) {
    px[k] = pos[(i0 + k) * 3 + 0];
    py[k] = pos[(i0 + k) * 3 + 1];
    pz[k] = pos[(i0 + k) * 3 + 2];
    sx[i0 + k] = px[k]; sy[i0 + k] = py[k]; sz[i0 + k] = pz[k];
    dd[k] = __builtin_inff();
  }
  float fx = pos[0], fy = pos[1], fz = pos[2];
  if (tid == 0) {
    out_idx[(size_t)b * NSAMP] = 0;
    if (out_pos) {
      out_pos[(size_t)b * NSAMP * 3 + 0] = fx;
      out_pos[(size_t)b * NSAMP * 3 + 1] = fy;
      out_pos[(size_t)b * NSAMP * 3 + 2] = fz;
    }
  }
  __syncthreads();

  for (int s = 1; s < NSAMP; ++s) {
    float lv = -__builtin_inff();
    int li = 0;
#pragma unroll
    for (int k = 0; k < PT; ++k) {
      float d = exact_d2(px[k], py[k], pz[k], fx, fy, fz);
      float nd = fminf(dd[k], d);
      dd[k] = nd;
      bool gt = nd > lv;  // strict >: first k within thread wins ties
      lv = gt ? nd : lv;
      li = gt ? k : li;
    }
    const float wv = wave_max_dpp(lv);
    const uint64_t mball = __ballot(lv == wv);
    const int wl = (int)__ffsll((unsigned long long)mball) - 1;  // lowest lane
    const int par = s & 1;
    if (lane == wl) {
      swk[par * 4 + wid] =
          ((uint64_t)__float_as_uint(wv) << 32) | (unsigned)(NPTS - 1 - (i0 + li));
    }
    lds_barrier();  // key visible; vmcnt NOT drained
    const uint64_t* kp = swk + par * 4;
    const uint64_t ka = kp[0], kb = kp[1], kc = kp[2], kd = kp[3];
    const uint64_t k01 = kb > ka ? kb : ka;
    const uint64_t k23 = kd > kc ? kd : kc;
    const uint64_t kfin = k23 > k01 ? k23 : k01;
    const int widx = (NPTS - 1) - (int)(unsigned)(kfin & 0xFFFFFFFFu);
    fx = sx[widx]; fy = sy[widx]; fz = sz[widx];  // broadcast reads, bit-exact copies
    if (tid == 0) {
      out_idx[(size_t)b * NSAMP + s] = widx;
      if (out_pos) {
        out_pos[((size_t)b * NSAMP + s) * 3 + 0] = fx;
        out_pos[((size_t)b * NSAMP + s) * 3 + 1] = fy;
        out_pos[((size_t)b * NSAMP + s) * 3 + 2] = fz;
      }
    }
  }
}

// ---- exact neighbor selection: in-radius candidates, 64 nearest (d, then j) ----
// Slot loops are guarded by the wave-uniform scalar scnt: slots entirely >= cnt
// hold e = ~0 and contribute 0 to every count/compaction -> skipping is exact.
template <int NPTS, int CAP>
__device__ __forceinline__ int select_neighbors(const float* __restrict__ bpos,
                                                float qx, float qy, float qz, float r2,
                                                char* wmem, unsigned* jl) {
  constexpr int SLOTS = CAP / 64;
  const int lane = LANE;
  uint64_t* list = (uint64_t*)wmem;
  const uint64_t ltmask = (1ull << lane) - 1ull;

  unsigned cnt = 0;
  for (int base = 0; base < NPTS; base += 64) {
    int j = base + lane;
    float d = exact_d2(bpos[j * 3], bpos[j * 3 + 1], bpos[j * 3 + 2], qx, qy, qz);
    bool pred = d < r2;
    uint64_t mask = __ballot(pred);
    if (pred) {
      unsigned p = cnt + (unsigned)__popcll(mask & ltmask);
      if (p < CAP) list[p] = ((uint64_t)__float_as_uint(d) << 32) | (unsigned)j;
    }
    cnt += (unsigned)__popcll(mask);
  }
  if (cnt > CAP) cnt = CAP;
  lds_fence();

  int m;
  if (cnt <= 64) {
    m = (int)cnt;
    jl[lane] = (lane < m) ? (unsigned)list[lane] : 0u;
  } else {
    m = 64;
    const unsigned scnt = __builtin_amdgcn_readfirstlane(cnt);  // scalar branches
    uint64_t e[SLOTS];
#pragma unroll
    for (int si = 0; si < SLOTS; ++si) {
      e[si] = ~0ull;
      if ((unsigned)(si * 64) < scnt) {
        int p = lane + 64 * si;
        e[si] = (p < (int)cnt) ? list[p] : ~0ull;
      }
    }
    // binary search for d* = 64th smallest distance bit-pattern, range [0, r2bits]
    unsigned lo = 0, hi = __float_as_uint(r2);
    while (lo < hi) {
      unsigned mid = (lo + hi) >> 1;
      unsigned c = 0;
#pragma unroll
      for (int si = 0; si < SLOTS; ++si)
        if ((unsigned)(si * 64) < scnt)
          c += (unsigned)__popcll(__ballot((unsigned)(e[si] >> 32) <= mid));
      if (c >= 64u) hi = mid; else lo = mid + 1;
    }
    const unsigned dstar = lo;
    unsigned nlt = 0, nt = 0;
#pragma unroll
    for (int si = 0; si < SLOTS; ++si)
      if ((unsigned)(si * 64) < scnt) {
        unsigned hb = (unsigned)(e[si] >> 32);
        nlt += (unsigned)__popcll(__ballot(hb < dstar));
        nt += (unsigned)__popcll(__ballot(hb == dstar));
      }
    const unsigned need = 64u - nlt;
    unsigned jsel = 0xFFFFFFFFu;
    if (nt != need) {  // distance tie at the cut -> keep `need` smallest j
      unsigned jlo = 0, jhi = (unsigned)NPTS - 1;
      while (jlo < jhi) {
        unsigned jmid = (jlo + jhi) >> 1;
        unsigned c = 0;
#pragma unroll
        for (int si = 0; si < SLOTS; ++si)
          if ((unsigned)(si * 64) < scnt)
            c += (unsigned)__popcll(__ballot(
                ((unsigned)(e[si] >> 32) == dstar) && ((unsigned)e[si] <= jmid)));
        if (c >= need) jhi = jmid; else jlo = jmid + 1;
      }
      jsel = jlo;
    }
    unsigned c2 = 0;
#pragma unroll
    for (int si = 0; si < SLOTS; ++si)
      if ((unsigned)(si * 64) < scnt) {
        unsigned hb = (unsigned)(e[si] >> 32), jj = (unsigned)e[si];
        bool p = (hb < dstar) || ((hb == dstar) && (jj <= jsel));
        uint64_t mask = __ballot(p);
        if (p) jl[c2 + (unsigned)__popcll(mask & ltmask)] = jj;
        c2 += (unsigned)__popcll(mask);
      }
  }
  lds_fence();
  return m;
}

// ---------------- conv1: H=64, lane = neighbor, y1[64] in regs ----------------
__device__ void conv1_body(const float* __restrict__ pos, const float* __restrict__ feats,
                           const float* __restrict__ w1, const float* __restrict__ b1,
                           const float* __restrict__ w2t, const float* __restrict__ b2,
                           float* __restrict__ out, int qid, char* wmem) {
  const int lane = LANE;
  const int b = qid >> 12, qi = qid & 4095;
  const float* bpos = pos + (size_t)b * 4096 * 3;
  const float qx = bpos[qi * 3 + 0], qy = bpos[qi * 3 + 1], qz = bpos[qi * 3 + 2];
  unsigned* jl = (unsigned*)(wmem + 8320);
  const int m = select_neighbors<4096, 512>(bpos, qx, qy, qz, 0.04f, wmem, jl);

  const bool valid = lane < m;
  const int j = valid ? (int)jl[lane] : 0;
  const float rx = bpos[j * 3 + 0] - qx;
  const float ry = bpos[j * 3 + 1] - qy;
  const float rz = bpos[j * 3 + 2] - qz;
  const float* xr = feats + ((size_t)b * 4096 + j) * 6;
  const float x0 = xr[0], x1 = xr[1], x2 = xr[2], x3 = xr[3], x4 = xr[4], x5 = xr[5];
  const float* w1r = w1 + 6 * 64;

  float y1[64];
#pragma unroll
  for (int f = 0; f < 64; ++f) {
    float a = b1[f];
    a = fmaf(x0, w1[0 * 64 + f], a);
    a = fmaf(x1, w1[1 * 64 + f], a);
    a = fmaf(x2, w1[2 * 64 + f], a);
    a = fmaf(x3, w1[3 * 64 + f], a);
    a = fmaf(x4, w1[4 * 64 + f], a);
    a = fmaf(x5, w1[5 * 64 + f], a);
    a = fmaf(rx, w1r[0 * 64 + f], a);
    a = fmaf(ry, w1r[1 * 64 + f], a);
    a = fmaf(rz, w1r[2 * 64 + f], a);
    y1[f] = fmaxf(a, 0.0f);
  }

  float* stg = (float*)wmem;  // [32][65], reuses candidate area
  float* orow = out + (size_t)qid * 64;
  const float NEG = -__builtin_inff();
#pragma unroll 1
  for (int cst = 0; cst < 64; cst += 32) {
    lds_fence();
#pragma unroll 2
    for (int g = 0; g < 32; ++g) {
      const float* wrow = w2t + (size_t)(cst + g) * 64;  // uniform -> s_load
      float a0 = 0.f, a1 = 0.f, a2 = 0.f, a3 = 0.f;
#pragma unroll
      for (int f = 0; f < 64; f += 4) {
        a0 = fmaf(y1[f], wrow[f], a0);
        a1 = fmaf(y1[f + 1], wrow[f + 1], a1);
        a2 = fmaf(y1[f + 2], wrow[f + 2], a2);
        a3 = fmaf(y1[f + 3], wrow[f + 3], a3);
      }
      float acc = b2[cst + g] + ((a0 + a1) + (a2 + a3));
      stg[g * 65 + lane] = valid ? acc : NEG;
    }
    lds_fence();
    const int r = lane & 31, jb = lane & 32;
    float mx = NEG;
#pragma unroll
    for (int t = 0; t < 32; ++t) mx = fmaxf(mx, stg[r * 65 + jb + t]);
    mx = fmaxf(mx, __shfl_xor(mx, 32));
    if (lane < 32) orow[cst + lane] = mx;
  }
}

// ------- conv2: H=128, TWO waves per query (wave-uniform feature half) -------
__device__ void conv2_body(const float* __restrict__ pos, const float* __restrict__ u,
                           const float* __restrict__ w1r, const float* __restrict__ w2t,
                           const float* __restrict__ b2, float* __restrict__ out,
                           int qid, int half, char* wmem, char* pairmem) {
  const int lane = LANE;
  const int b = qid >> 11, qi = qid & 2047;
  const float* bpos = pos + (size_t)b * 2048 * 3;
  const float qx = bpos[qi * 3 + 0], qy = bpos[qi * 3 + 1], qz = bpos[qi * 3 + 2];
  unsigned* jl = (unsigned*)(wmem + 8320);
  const int m = select_neighbors<2048, 1024>(bpos, qx, qy, qz, 0.16f, wmem, jl);
  const int fh = half * 64;

  const bool valid = lane < m;
  const int j = valid ? (int)jl[lane] : 0;
  const float rx = bpos[j * 3 + 0] - qx;
  const float ry = bpos[j * 3 + 1] - qy;
  const float rz = bpos[j * 3 + 2] - qz;
  const float* urow = u + ((size_t)b * 2048 + j) * 128 + fh;

  float y1[64];
#pragma unroll
  for (int t = 0; t < 64; t += 4) {
    float4 v = *reinterpret_cast<const float4*>(urow + t);
    y1[t] = v.x; y1[t + 1] = v.y; y1[t + 2] = v.z; y1[t + 3] = v.w;
  }
#pragma unroll
  for (int t = 0; t < 64; ++t) {
    float a = fmaf(rx, w1r[0 * 128 + fh + t], y1[t]);
    a = fmaf(ry, w1r[1 * 128 + fh + t], a);
    a = fmaf(rz, w1r[2 * 128 + fh + t], a);
    y1[t] = fmaxf(a, 0.0f);
  }

  float* stgA = (float*)pairmem;           // half-0 wave's [32][65]
  float* stgB = (float*)(pairmem + 8704);  // half-1 wave's [32][65]
  float* stg_own = half ? stgB : stgA;     // == wmem
  float* orow = out + (size_t)qid * 128;
  const float NEG = -__builtin_inff();
#pragma unroll 1
  for (int cst = 0; cst < 128; cst += 32) {
#pragma unroll 2
    for (int g = 0; g < 32; ++g) {
      const float* wrow = w2t + (size_t)(cst + g) * 128 + fh;  // uniform -> s_load
      float a0 = 0.f, a1 = 0.f, a2 = 0.f, a3 = 0.f;
#pragma unroll
      for (int t = 0; t < 64; t += 4) {
        a0 = fmaf(y1[t], wrow[t], a0);
        a1 = fmaf(y1[t + 1], wrow[t + 1], a1);
        a2 = fmaf(y1[t + 2], wrow[t + 2], a2);
        a3 = fmaf(y1[t + 3], wrow[t + 3], a3);
      }
      float pc = (a0 + a1) + (a2 + a3);
      stg_own[g * 65 + lane] = valid ? pc : (half ? 0.0f : NEG);
    }
    __syncthreads();
    if (half == 0) {
      const int r = lane & 31, jb = (lane >> 5) * 32;
      float mx = NEG;
#pragma unroll
      for (int t = 0; t < 32; ++t)
        mx = fmaxf(mx, stgA[r * 65 + jb + t] + stgB[r * 65 + jb + t]);
      mx = fmaxf(mx, __shfl_xor(mx, 32));
      if (lane < 32) orow[cst + lane] = mx + b2[cst + lane];
    }
    __syncthreads();
  }
}

// ---------------- fused stage kernels: blocks 0..7 = FPS, rest = conv ----------------
__global__ __launch_bounds__(256, 2) void stage1_kernel(
    const float* __restrict__ coords, const float* __restrict__ feats,
    const float* __restrict__ w1, const float* __restrict__ b1,
    const float* __restrict__ w2t, const float* __restrict__ b2,
    float* __restrict__ out, int* __restrict__ fps_idx, float* __restrict__ fps_pos) {
  __shared__ __align__(16) char smem[49216];  // fps: 48KB table + keys; conv: 4 x 9088
  if (blockIdx.x < 8) {
    fps_body<4096, 2048>(coords, (int)blockIdx.x, fps_idx, fps_pos, smem);
  } else {
    int qid = __builtin_amdgcn_readfirstlane(((int)blockIdx.x - 8) * 4 + WID);
    conv1_body(coords, feats, w1, b1, w2t, b2, out, qid, smem + WID * 9088);
  }
}

// 4 blocks/CU (LDS 34816, VGPR cap 128): extra conv2 waves hide s_load stalls.
__global__ __launch_bounds__(256, 4) void stage2_kernel(
    const float* __restrict__ p1, const float* __restrict__ u2,
    const float* __restrict__ w1r, const float* __restrict__ w2t,
    const float* __restrict__ b2, float* __restrict__ out,
    int* __restrict__ fps_idx) {
  __shared__ __align__(16) char smem[34816];  // fps: 24KB+keys; conv: 4 x 8704
  if (blockIdx.x < 8) {
    fps_body<2048, 512>(p1, (int)blockIdx.x, fps_idx, nullptr, smem);
  } else {
    const int wid = WID;
    const int half = __builtin_amdgcn_readfirstlane(wid & 1);
    const int qid =
        __builtin_amdgcn_readfirstlane(((int)blockIdx.x - 8) * 2 + (wid >> 1));
    conv2_body(p1, u2, w1r, w2t, b2, out, qid, half, smem + wid * 8704,
               smem + (wid & ~1) * 8704);
  }
}

// ------- u2 = b1b + h1[i1] @ W1b_feat (layer-1 factoring for stage 2) -------
__global__ __launch_bounds__(128) void u2_kernel(const float* __restrict__ h1,
                                                 const int* __restrict__ i1,
                                                 const float* __restrict__ w1,
                                                 const float* __restrict__ b1,
                                                 float* __restrict__ u2) {
  int row = blockIdx.x;  // 16384
  int f = (int)threadIdx.x;
  int b = row >> 11;
  int src = i1[row];
  const float* x = h1 + ((size_t)b * 4096 + src) * 64;
  float acc = b1[f];
#pragma unroll
  for (int k = 0; k < 64; ++k) acc = fmaf(x[k], w1[k * 128 + f], acc);
  u2[(size_t)row * 128 + f] = acc;
}

__global__ __launch_bounds__(256) void transpose_kernel(const float* __restrict__ w2a,
                                                        const float* __restrict__ w2b,
                                                        float* __restrict__ w2ta,
                                                        float* __restrict__ w2tb) {
  int gtid = blockIdx.x * 256 + (int)threadIdx.x;
  int stride = gridDim.x * 256;
  for (int t = gtid; t < 64 * 64; t += stride) w2ta[(t & 63) * 64 + (t >> 6)] = w2a[t];
  for (int t = gtid; t < 128 * 128; t += stride) w2tb[(t & 127) * 128 + (t >> 7)] = w2b[t];
}

// ---------------- global max pool over i2 + final linear ----------------
__global__ __launch_bounds__(512) void pool_linear_kernel(
    const float* __restrict__ h2, const int* __restrict__ i2,
    const float* __restrict__ wl, const float* __restrict__ bl,
    float* __restrict__ out) {
  int b = blockIdx.x;
  int c = (int)threadIdx.x >> 7;
  int f = (int)threadIdx.x & 127;
  __shared__ float part[4][128];
  __shared__ float feat[128];
  float mx = -__builtin_inff();
  const int* idx = i2 + b * 512;
  for (int s = c * 128; s < c * 128 + 128; ++s) {
    int j = idx[s];
    mx = fmaxf(mx, h2[((size_t)b * 2048 + j) * 128 + f]);
  }
  part[c][f] = mx;
  __syncthreads();
  if (c == 0) {
    feat[f] = fmaxf(fmaxf(part[0][f], part[1][f]), fmaxf(part[2][f], part[3][f]));
  }
  __syncthreads();
  if (c == 0) {
    float acc = bl[f];
#pragma unroll
    for (int k = 0; k < 128; ++k) acc = fmaf(feat[k], wl[k * 128 + f], acc);
    out[b * 128 + f] = acc;
  }
}

extern "C" void kernel_launch(void* const* d_in, const int* in_sizes, int n_in,
                              void* d_out, int out_size, void* d_ws, size_t ws_size,
                              hipStream_t stream) {
  const float* feats = (const float*)d_in[0];   // [8,4096,6]
  const float* coords = (const float*)d_in[1];  // [8,4096,3]
  const float* W1a = (const float*)d_in[2];     // [9,64]
  const float* b1a = (const float*)d_in[3];
  const float* W2a = (const float*)d_in[4];     // [64,64]
  const float* b2a = (const float*)d_in[5];
  const float* W1b = (const float*)d_in[6];     // [67,128]
  const float* b1b = (const float*)d_in[7];
  const float* W2b = (const float*)d_in[8];     // [128,128]
  const float* b2b = (const float*)d_in[9];
  const float* Wl = (const float*)d_in[10];     // [128,128]
  const float* bl = (const float*)d_in[11];

  float* ws = (float*)d_ws;
  float* W2TA = ws;                  // 4096
  float* W2TB = W2TA + 4096;         // 16384
  float* H1 = W2TB + 16384;          // 8*4096*64  = 2097152
  float* U2 = H1 + 2097152;          // 8*2048*128 = 2097152
  float* H2 = U2 + 2097152;          // 8*2048*128 = 2097152
  float* P1 = H2 + 2097152;          // 8*2048*3   = 49152
  int* I1 = (int*)(P1 + 49152);      // 8*2048
  int* I2 = I1 + 16384;              // 8*512

  transpose_kernel<<<80, 256, 0, stream>>>(W2a, W2b, W2TA, W2TB);
  // stage 1: fps1 (blocks 0-7) || conv1 (8192 blocks x 4 queries)
  stage1_kernel<<<8 + 8192, 256, 0, stream>>>(coords, feats, W1a, b1a, W2TA, b2a, H1,
                                              I1, P1);
  u2_kernel<<<16384, 128, 0, stream>>>(H1, I1, W1b, b1b, U2);
  // stage 2: fps2 (blocks 0-7) || conv2 (8192 blocks x 2 queries x 2 waves)
  stage2_kernel<<<8 + 8192, 256, 0, stream>>>(P1, U2, W1b + 64 * 128, W2TB, b2b, H2, I2);
  pool_linear_kernel<<<8, 512, 0, stream>>>(H2, I2, Wl, bl, (float*)d_out);
}

// Round 13
// 2553.852 us; speedup vs baseline: 1.1858x; 1.1858x over previous
//
#include <hip/hip_runtime.h>
#include <stdint.h>

#define LANE ((int)(threadIdx.x & 63))
#define WID  ((int)(threadIdx.x >> 6))

__device__ __forceinline__ float exact_d2(float ax, float ay, float az,
                                          float bx, float by, float bz) {
  float dx = ax - bx, dy = ay - by, dz = az - bz;
  return __fadd_rn(__fadd_rn(__fmul_rn(dx, dx), __fmul_rn(dy, dy)), __fmul_rn(dz, dz));
}

__device__ __forceinline__ void lds_fence() {
  asm volatile("s_waitcnt lgkmcnt(0)" ::: "memory");
}

// Barrier that does NOT drain vmcnt: LDS-visibility fence + raw s_barrier.
__device__ __forceinline__ void lds_barrier() {
  asm volatile("s_waitcnt lgkmcnt(0)" ::: "memory");
  __builtin_amdgcn_s_barrier();
  asm volatile("" ::: "memory");
}

// Wave-wide max via DPP. ROW_SHR 1/2/4/8 accumulates row maxima into lanes
// 15/31/47/63; row_bcast15 (rows 1,3) then row_bcast31 (rows 2,3) fold rows;
// lane 63 holds the full wave max. (R7-verified.)
__device__ __forceinline__ float wave_max_dpp(float v) {
  const int NI = 0xff800000;  // -inf bits: identity
  int x = __float_as_int(v);
  x = __float_as_int(fmaxf(__int_as_float(x),
      __int_as_float(__builtin_amdgcn_update_dpp(NI, x, 0x111, 0xf, 0xf, false))));
  x = __float_as_int(fmaxf(__int_as_float(x),
      __int_as_float(__builtin_amdgcn_update_dpp(NI, x, 0x112, 0xf, 0xf, false))));
  x = __float_as_int(fmaxf(__int_as_float(x),
      __int_as_float(__builtin_amdgcn_update_dpp(NI, x, 0x114, 0xf, 0xf, false))));
  x = __float_as_int(fmaxf(__int_as_float(x),
      __int_as_float(__builtin_amdgcn_update_dpp(NI, x, 0x118, 0xf, 0xf, false))));
  x = __float_as_int(fmaxf(__int_as_float(x),
      __int_as_float(__builtin_amdgcn_update_dpp(NI, x, 0x142, 0xa, 0xf, false))));
  x = __float_as_int(fmaxf(__int_as_float(x),
      __int_as_float(__builtin_amdgcn_update_dpp(NI, x, 0x143, 0xc, 0xf, false))));
  return __int_as_float(__builtin_amdgcn_readlane(x, 63));
}

// ---------------- FPS body: symmetric waves, keys-only LDS round (R8/R10) --------
template <int NPTS, int NSAMP>
__device__ void fps_body(const float* __restrict__ coords, int b,
                         int* __restrict__ out_idx, float* __restrict__ out_pos,
                         char* smem_raw) {
  constexpr int PT = NPTS / 256;
  float* sx = (float*)smem_raw;                 // [NPTS]
  float* sy = sx + NPTS;                        // [NPTS]
  float* sz = sy + NPTS;                        // [NPTS]
  uint64_t* swk = (uint64_t*)(sz + NPTS);       // [2][4] keys
  const float* pos = coords + (size_t)b * NPTS * 3;
  const int tid = (int)threadIdx.x;
  const int lane = LANE, wid = WID;

  __builtin_amdgcn_s_setprio(3);  // FPS is the serial critical path

  float px[PT], py[PT], pz[PT], dd[PT];
  const int i0 = tid * PT;
#pragma unroll
  for (int k = 0; k < PT; ++k) {
    px[k] = pos[(i0 + k) * 3 + 0];
    py[k] = pos[(i0 + k) * 3 + 1];
    pz[k] = pos[(i0 + k) * 3 + 2];
    sx[i0 + k] = px[k]; sy[i0 + k] = py[k]; sz[i0 + k] = pz[k];
    dd[k] = __builtin_inff();
  }
  float fx = pos[0], fy = pos[1], fz = pos[2];
  if (tid == 0) {
    out_idx[(size_t)b * NSAMP] = 0;
    if (out_pos) {
      out_pos[(size_t)b * NSAMP * 3 + 0] = fx;
      out_pos[(size_t)b * NSAMP * 3 + 1] = fy;
      out_pos[(size_t)b * NSAMP * 3 + 2] = fz;
    }
  }
  __syncthreads();

  for (int s = 1; s < NSAMP; ++s) {
    float lv = -__builtin_inff();
    int li = 0;
#pragma unroll
    for (int k = 0; k < PT; ++k) {
      float d = exact_d2(px[k], py[k], pz[k], fx, fy, fz);
      float nd = fminf(dd[k], d);
      dd[k] = nd;
      bool gt = nd > lv;  // strict >: first k within thread wins ties
      lv = gt ? nd : lv;
      li = gt ? k : li;
    }
    const float wv = wave_max_dpp(lv);
    const uint64_t mball = __ballot(lv == wv);
    const int wl = (int)__ffsll((unsigned long long)mball) - 1;  // lowest lane
    const int par = s & 1;
    if (lane == wl) {
      swk[par * 4 + wid] =
          ((uint64_t)__float_as_uint(wv) << 32) | (unsigned)(NPTS - 1 - (i0 + li));
    }
    lds_barrier();  // key visible; vmcnt NOT drained
    const uint64_t* kp = swk + par * 4;
    const uint64_t ka = kp[0], kb = kp[1], kc = kp[2], kd = kp[3];
    const uint64_t k01 = kb > ka ? kb : ka;
    const uint64_t k23 = kd > kc ? kd : kc;
    const uint64_t kfin = k23 > k01 ? k23 : k01;
    const int widx = (NPTS - 1) - (int)(unsigned)(kfin & 0xFFFFFFFFu);
    fx = sx[widx]; fy = sy[widx]; fz = sz[widx];  // broadcast reads, bit-exact copies
    if (tid == 0) {
      out_idx[(size_t)b * NSAMP + s] = widx;
      if (out_pos) {
        out_pos[((size_t)b * NSAMP + s) * 3 + 0] = fx;
        out_pos[((size_t)b * NSAMP + s) * 3 + 1] = fy;
        out_pos[((size_t)b * NSAMP + s) * 3 + 2] = fz;
      }
    }
  }
}

// ---- exact neighbor selection: in-radius candidates, 64 nearest (d, then j) ----
// Slot loops are guarded by the wave-uniform scalar scnt: slots entirely >= cnt
// hold e = ~0 and contribute 0 to every count/compaction -> skipping is exact.
template <int NPTS, int CAP>
__device__ __forceinline__ int select_neighbors(const float* __restrict__ bpos,
                                                float qx, float qy, float qz, float r2,
                                                char* wmem, unsigned* jl) {
  constexpr int SLOTS = CAP / 64;
  const int lane = LANE;
  uint64_t* list = (uint64_t*)wmem;
  const uint64_t ltmask = (1ull << lane) - 1ull;

  unsigned cnt = 0;
  for (int base = 0; base < NPTS; base += 64) {
    int j = base + lane;
    float d = exact_d2(bpos[j * 3], bpos[j * 3 + 1], bpos[j * 3 + 2], qx, qy, qz);
    bool pred = d < r2;
    uint64_t mask = __ballot(pred);
    if (pred) {
      unsigned p = cnt + (unsigned)__popcll(mask & ltmask);
      if (p < CAP) list[p] = ((uint64_t)__float_as_uint(d) << 32) | (unsigned)j;
    }
    cnt += (unsigned)__popcll(mask);
  }
  if (cnt > CAP) cnt = CAP;
  lds_fence();

  int m;
  if (cnt <= 64) {
    m = (int)cnt;
    jl[lane] = (lane < m) ? (unsigned)list[lane] : 0u;
  } else {
    m = 64;
    const unsigned scnt = __builtin_amdgcn_readfirstlane(cnt);  // scalar branches
    uint64_t e[SLOTS];
#pragma unroll
    for (int si = 0; si < SLOTS; ++si) {
      e[si] = ~0ull;
      if ((unsigned)(si * 64) < scnt) {
        int p = lane + 64 * si;
        e[si] = (p < (int)cnt) ? list[p] : ~0ull;
      }
    }
    // binary search for d* = 64th smallest distance bit-pattern, range [0, r2bits]
    unsigned lo = 0, hi = __float_as_uint(r2);
    while (lo < hi) {
      unsigned mid = (lo + hi) >> 1;
      unsigned c = 0;
#pragma unroll
      for (int si = 0; si < SLOTS; ++si)
        if ((unsigned)(si * 64) < scnt)
          c += (unsigned)__popcll(__ballot((unsigned)(e[si] >> 32) <= mid));
      if (c >= 64u) hi = mid; else lo = mid + 1;
    }
    const unsigned dstar = lo;
    unsigned nlt = 0, nt = 0;
#pragma unroll
    for (int si = 0; si < SLOTS; ++si)
      if ((unsigned)(si * 64) < scnt) {
        unsigned hb = (unsigned)(e[si] >> 32);
        nlt += (unsigned)__popcll(__ballot(hb < dstar));
        nt += (unsigned)__popcll(__ballot(hb == dstar));
      }
    const unsigned need = 64u - nlt;
    unsigned jsel = 0xFFFFFFFFu;
    if (nt != need) {  // distance tie at the cut -> keep `need` smallest j
      unsigned jlo = 0, jhi = (unsigned)NPTS - 1;
      while (jlo < jhi) {
        unsigned jmid = (jlo + jhi) >> 1;
        unsigned c = 0;
#pragma unroll
        for (int si = 0; si < SLOTS; ++si)
          if ((unsigned)(si * 64) < scnt)
            c += (unsigned)__popcll(__ballot(
                ((unsigned)(e[si] >> 32) == dstar) && ((unsigned)e[si] <= jmid)));
        if (c >= need) jhi = jmid; else jlo = jmid + 1;
      }
      jsel = jlo;
    }
    unsigned c2 = 0;
#pragma unroll
    for (int si = 0; si < SLOTS; ++si)
      if ((unsigned)(si * 64) < scnt) {
        unsigned hb = (unsigned)(e[si] >> 32), jj = (unsigned)e[si];
        bool p = (hb < dstar) || ((hb == dstar) && (jj <= jsel));
        uint64_t mask = __ballot(p);
        if (p) jl[c2 + (unsigned)__popcll(mask & ltmask)] = jj;
        c2 += (unsigned)__popcll(mask);
      }
  }
  lds_fence();
  return m;
}

// ---------------- conv1: H=64, lane = neighbor, y1[64] in regs ----------------
__device__ void conv1_body(const float* __restrict__ pos, const float* __restrict__ feats,
                           const float* __restrict__ w1, const float* __restrict__ b1,
                           const float* __restrict__ w2t, const float* __restrict__ b2,
                           float* __restrict__ out, int qid, char* wmem) {
  const int lane = LANE;
  const int b = qid >> 12, qi = qid & 4095;
  const float* bpos = pos + (size_t)b * 4096 * 3;
  const float qx = bpos[qi * 3 + 0], qy = bpos[qi * 3 + 1], qz = bpos[qi * 3 + 2];
  unsigned* jl = (unsigned*)(wmem + 8320);
  const int m = select_neighbors<4096, 512>(bpos, qx, qy, qz, 0.04f, wmem, jl);

  const bool valid = lane < m;
  const int j = valid ? (int)jl[lane] : 0;
  const float rx = bpos[j * 3 + 0] - qx;
  const float ry = bpos[j * 3 + 1] - qy;
  const float rz = bpos[j * 3 + 2] - qz;
  const float* xr = feats + ((size_t)b * 4096 + j) * 6;
  const float x0 = xr[0], x1 = xr[1], x2 = xr[2], x3 = xr[3], x4 = xr[4], x5 = xr[5];
  const float* w1r = w1 + 6 * 64;

  float y1[64];
#pragma unroll
  for (int f = 0; f < 64; ++f) {
    float a = b1[f];
    a = fmaf(x0, w1[0 * 64 + f], a);
    a = fmaf(x1, w1[1 * 64 + f], a);
    a = fmaf(x2, w1[2 * 64 + f], a);
    a = fmaf(x3, w1[3 * 64 + f], a);
    a = fmaf(x4, w1[4 * 64 + f], a);
    a = fmaf(x5, w1[5 * 64 + f], a);
    a = fmaf(rx, w1r[0 * 64 + f], a);
    a = fmaf(ry, w1r[1 * 64 + f], a);
    a = fmaf(rz, w1r[2 * 64 + f], a);
    y1[f] = fmaxf(a, 0.0f);
  }

  float* stg = (float*)wmem;  // [32][65], reuses candidate area
  float* orow = out + (size_t)qid * 64;
  const float NEG = -__builtin_inff();
#pragma unroll 1
  for (int cst = 0; cst < 64; cst += 32) {
    lds_fence();
#pragma unroll 2
    for (int g = 0; g < 32; ++g) {
      const float* wrow = w2t + (size_t)(cst + g) * 64;  // uniform -> s_load
      float a0 = 0.f, a1 = 0.f, a2 = 0.f, a3 = 0.f;
#pragma unroll
      for (int f = 0; f < 64; f += 4) {
        a0 = fmaf(y1[f], wrow[f], a0);
        a1 = fmaf(y1[f + 1], wrow[f + 1], a1);
        a2 = fmaf(y1[f + 2], wrow[f + 2], a2);
        a3 = fmaf(y1[f + 3], wrow[f + 3], a3);
      }
      float acc = b2[cst + g] + ((a0 + a1) + (a2 + a3));
      stg[g * 65 + lane] = valid ? acc : NEG;
    }
    lds_fence();
    const int r = lane & 31, jb = lane & 32;
    float mx = NEG;
#pragma unroll
    for (int t = 0; t < 32; ++t) mx = fmaxf(mx, stg[r * 65 + jb + t]);
    mx = fmaxf(mx, __shfl_xor(mx, 32));
    if (lane < 32) orow[cst + lane] = mx;
  }
}

// ------- conv2: H=128, TWO waves per query (wave-uniform feature half) -------
__device__ void conv2_body(const float* __restrict__ pos, const float* __restrict__ u,
                           const float* __restrict__ w1r, const float* __restrict__ w2t,
                           const float* __restrict__ b2, float* __restrict__ out,
                           int qid, int half, char* wmem, char* pairmem) {
  const int lane = LANE;
  const int b = qid >> 11, qi = qid & 2047;
  const float* bpos = pos + (size_t)b * 2048 * 3;
  const float qx = bpos[qi * 3 + 0], qy = bpos[qi * 3 + 1], qz = bpos[qi * 3 + 2];
  unsigned* jl = (unsigned*)(wmem + 8320);
  const int m = select_neighbors<2048, 1024>(bpos, qx, qy, qz, 0.16f, wmem, jl);
  const int fh = half * 64;

  const bool valid = lane < m;
  const int j = valid ? (int)jl[lane] : 0;
  const float rx = bpos[j * 3 + 0] - qx;
  const float ry = bpos[j * 3 + 1] - qy;
  const float rz = bpos[j * 3 + 2] - qz;
  const float* urow = u + ((size_t)b * 2048 + j) * 128 + fh;

  float y1[64];
#pragma unroll
  for (int t = 0; t < 64; t += 4) {
    float4 v = *reinterpret_cast<const float4*>(urow + t);
    y1[t] = v.x; y1[t + 1] = v.y; y1[t + 2] = v.z; y1[t + 3] = v.w;
  }
#pragma unroll
  for (int t = 0; t < 64; ++t) {
    float a = fmaf(rx, w1r[0 * 128 + fh + t], y1[t]);
    a = fmaf(ry, w1r[1 * 128 + fh + t], a);
    a = fmaf(rz, w1r[2 * 128 + fh + t], a);
    y1[t] = fmaxf(a, 0.0f);
  }

  float* stgA = (float*)pairmem;           // half-0 wave's [32][65]
  float* stgB = (float*)(pairmem + 8704);  // half-1 wave's [32][65]
  float* stg_own = half ? stgB : stgA;     // == wmem
  float* orow = out + (size_t)qid * 128;
  const float NEG = -__builtin_inff();
#pragma unroll 1
  for (int cst = 0; cst < 128; cst += 32) {
#pragma unroll 2
    for (int g = 0; g < 32; ++g) {
      const float* wrow = w2t + (size_t)(cst + g) * 128 + fh;  // uniform -> s_load
      float a0 = 0.f, a1 = 0.f, a2 = 0.f, a3 = 0.f;
#pragma unroll
      for (int t = 0; t < 64; t += 4) {
        a0 = fmaf(y1[t], wrow[t], a0);
        a1 = fmaf(y1[t + 1], wrow[t + 1], a1);
        a2 = fmaf(y1[t + 2], wrow[t + 2], a2);
        a3 = fmaf(y1[t + 3], wrow[t + 3], a3);
      }
      float pc = (a0 + a1) + (a2 + a3);
      stg_own[g * 65 + lane] = valid ? pc : (half ? 0.0f : NEG);
    }
    __syncthreads();
    if (half == 0) {
      const int r = lane & 31, jb = (lane >> 5) * 32;
      float mx = NEG;
#pragma unroll
      for (int t = 0; t < 32; ++t)
        mx = fmaxf(mx, stgA[r * 65 + jb + t] + stgB[r * 65 + jb + t]);
      mx = fmaxf(mx, __shfl_xor(mx, 32));
      if (lane < 32) orow[cst + lane] = mx + b2[cst + lane];
    }
    __syncthreads();
  }
}

// ---------------- fused stage kernels: blocks 0..7 = FPS, rest = conv ----------------
__global__ __launch_bounds__(256, 2) void stage1_kernel(
    const float* __restrict__ coords, const float* __restrict__ feats,
    const float* __restrict__ w1, const float* __restrict__ b1,
    const float* __restrict__ w2t, const float* __restrict__ b2,
    float* __restrict__ out, int* __restrict__ fps_idx, float* __restrict__ fps_pos) {
  __shared__ __align__(16) char smem[49216];  // fps: 48KB table + keys; conv: 4 x 9088
  if (blockIdx.x < 8) {
    fps_body<4096, 2048>(coords, (int)blockIdx.x, fps_idx, fps_pos, smem);
  } else {
    int qid = __builtin_amdgcn_readfirstlane(((int)blockIdx.x - 8) * 4 + WID);
    conv1_body(coords, feats, w1, b1, w2t, b2, out, qid, smem + WID * 9088);
  }
}

// (256,2): VGPR cap 128 -- conv2 needs ~80; (.,4) would cap at 64 and spill (R12).
__global__ __launch_bounds__(256, 2) void stage2_kernel(
    const float* __restrict__ p1, const float* __restrict__ u2,
    const float* __restrict__ w1r, const float* __restrict__ w2t,
    const float* __restrict__ b2, float* __restrict__ out,
    int* __restrict__ fps_idx) {
  __shared__ __align__(16) char smem[34816];  // fps: 24KB+keys; conv: 4 x 8704
  if (blockIdx.x < 8) {
    fps_body<2048, 512>(p1, (int)blockIdx.x, fps_idx, nullptr, smem);
  } else {
    const int wid = WID;
    const int half = __builtin_amdgcn_readfirstlane(wid & 1);
    const int qid =
        __builtin_amdgcn_readfirstlane(((int)blockIdx.x - 8) * 2 + (wid >> 1));
    conv2_body(p1, u2, w1r, w2t, b2, out, qid, half, smem + wid * 8704,
               smem + (wid & ~1) * 8704);
  }
}

// ------- u2 = b1b + h1[i1] @ W1b_feat (layer-1 factoring for stage 2) -------
__global__ __launch_bounds__(128) void u2_kernel(const float* __restrict__ h1,
                                                 const int* __restrict__ i1,
                                                 const float* __restrict__ w1,
                                                 const float* __restrict__ b1,
                                                 float* __restrict__ u2) {
  int row = blockIdx.x;  // 16384
  int f = (int)threadIdx.x;
  int b = row >> 11;
  int src = i1[row];
  const float* x = h1 + ((size_t)b * 4096 + src) * 64;
  float acc = b1[f];
#pragma unroll
  for (int k = 0; k < 64; ++k) acc = fmaf(x[k], w1[k * 128 + f], acc);
  u2[(size_t)row * 128 + f] = acc;
}

__global__ __launch_bounds__(256) void transpose_kernel(const float* __restrict__ w2a,
                                                        const float* __restrict__ w2b,
                                                        float* __restrict__ w2ta,
                                                        float* __restrict__ w2tb) {
  int gtid = blockIdx.x * 256 + (int)threadIdx.x;
  int stride = gridDim.x * 256;
  for (int t = gtid; t < 64 * 64; t += stride) w2ta[(t & 63) * 64 + (t >> 6)] = w2a[t];
  for (int t = gtid; t < 128 * 128; t += stride) w2tb[(t & 127) * 128 + (t >> 7)] = w2b[t];
}

// ---------------- global max pool over i2 + final linear ----------------
__global__ __launch_bounds__(512) void pool_linear_kernel(
    const float* __restrict__ h2, const int* __restrict__ i2,
    const float* __restrict__ wl, const float* __restrict__ bl,
    float* __restrict__ out) {
  int b = blockIdx.x;
  int c = (int)threadIdx.x >> 7;
  int f = (int)threadIdx.x & 127;
  __shared__ float part[4][128];
  __shared__ float feat[128];
  float mx = -__builtin_inff();
  const int* idx = i2 + b * 512;
  for (int s = c * 128; s < c * 128 + 128; ++s) {
    int j = idx[s];
    mx = fmaxf(mx, h2[((size_t)b * 2048 + j) * 128 + f]);
  }
  part[c][f] = mx;
  __syncthreads();
  if (c == 0) {
    feat[f] = fmaxf(fmaxf(part[0][f], part[1][f]), fmaxf(part[2][f], part[3][f]));
  }
  __syncthreads();
  if (c == 0) {
    float acc = bl[f];
#pragma unroll
    for (int k = 0; k < 128; ++k) acc = fmaf(feat[k], wl[k * 128 + f], acc);
    out[b * 128 + f] = acc;
  }
}

extern "C" void kernel_launch(void* const* d_in, const int* in_sizes, int n_in,
                              void* d_out, int out_size, void* d_ws, size_t ws_size,
                              hipStream_t stream) {
  const float* feats = (const float*)d_in[0];   // [8,4096,6]
  const float* coords = (const float*)d_in[1];  // [8,4096,3]
  const float* W1a = (const float*)d_in[2];     // [9,64]
  const float* b1a = (const float*)d_in[3];
  const float* W2a = (const float*)d_in[4];     // [64,64]
  const float* b2a = (const float*)d_in[5];
  const float* W1b = (const float*)d_in[6];     // [67,128]
  const float* b1b = (const float*)d_in[7];
  const float* W2b = (const float*)d_in[8];     // [128,128]
  const float* b2b = (const float*)d_in[9];
  const float* Wl = (const float*)d_in[10];     // [128,128]
  const float* bl = (const float*)d_in[11];

  float* ws = (float*)d_ws;
  float* W2TA = ws;                  // 4096
  float* W2TB = W2TA + 4096;         // 16384
  float* H1 = W2TB + 16384;          // 8*4096*64  = 2097152
  float* U2 = H1 + 2097152;          // 8*2048*128 = 2097152
  float* H2 = U2 + 2097152;          // 8*2048*128 = 2097152
  float* P1 = H2 + 2097152;          // 8*2048*3   = 49152
  int* I1 = (int*)(P1 + 49152);      // 8*2048
  int* I2 = I1 + 16384;              // 8*512

  transpose_kernel<<<80, 256, 0, stream>>>(W2a, W2b, W2TA, W2TB);
  // stage 1: fps1 (blocks 0-7) || conv1 (8192 blocks x 4 queries)
  stage1_kernel<<<8 + 8192, 256, 0, stream>>>(coords, feats, W1a, b1a, W2TA, b2a, H1,
                                              I1, P1);
  u2_kernel<<<16384, 128, 0, stream>>>(H1, I1, W1b, b1b, U2);
  // stage 2: fps2 (blocks 0-7) || conv2 (8192 blocks x 2 queries x 2 waves)
  stage2_kernel<<<8 + 8192, 256, 0, stream>>>(P1, U2, W1b + 64 * 128, W2TB, b2b, H2, I2);
  pool_linear_kernel<<<8, 512, 0, stream>>>(H2, I2, Wl, bl, (float*)d_out);
}

// Round 14
// 2289.048 us; speedup vs baseline: 1.3230x; 1.1157x over previous
//
#include <hip/hip_runtime.h>
#include <stdint.h>

#define LANE ((int)(threadIdx.x & 63))
#define WID  ((int)(threadIdx.x >> 6))

__device__ __forceinline__ float exact_d2(float ax, float ay, float az,
                                          float bx, float by, float bz) {
  float dx = ax - bx, dy = ay - by, dz = az - bz;
  return __fadd_rn(__fadd_rn(__fmul_rn(dx, dx), __fmul_rn(dy, dy)), __fmul_rn(dz, dz));
}

__device__ __forceinline__ void lds_fence() {
  asm volatile("s_waitcnt lgkmcnt(0)" ::: "memory");
}

// Barrier that does NOT drain vmcnt: LDS-visibility fence + raw s_barrier.
__device__ __forceinline__ void lds_barrier() {
  asm volatile("s_waitcnt lgkmcnt(0)" ::: "memory");
  __builtin_amdgcn_s_barrier();
  asm volatile("" ::: "memory");
}

// Wave-wide max via DPP. ROW_SHR 1/2/4/8 accumulates row maxima into lanes
// 15/31/47/63; row_bcast15 (rows 1,3) then row_bcast31 (rows 2,3) fold rows;
// lane 63 holds the full wave max. (R7-verified.)
__device__ __forceinline__ float wave_max_dpp(float v) {
  const int NI = 0xff800000;  // -inf bits: identity
  int x = __float_as_int(v);
  x = __float_as_int(fmaxf(__int_as_float(x),
      __int_as_float(__builtin_amdgcn_update_dpp(NI, x, 0x111, 0xf, 0xf, false))));
  x = __float_as_int(fmaxf(__int_as_float(x),
      __int_as_float(__builtin_amdgcn_update_dpp(NI, x, 0x112, 0xf, 0xf, false))));
  x = __float_as_int(fmaxf(__int_as_float(x),
      __int_as_float(__builtin_amdgcn_update_dpp(NI, x, 0x114, 0xf, 0xf, false))));
  x = __float_as_int(fmaxf(__int_as_float(x),
      __int_as_float(__builtin_amdgcn_update_dpp(NI, x, 0x118, 0xf, 0xf, false))));
  x = __float_as_int(fmaxf(__int_as_float(x),
      __int_as_float(__builtin_amdgcn_update_dpp(NI, x, 0x142, 0xa, 0xf, false))));
  x = __float_as_int(fmaxf(__int_as_float(x),
      __int_as_float(__builtin_amdgcn_update_dpp(NI, x, 0x143, 0xc, 0xf, false))));
  return __int_as_float(__builtin_amdgcn_readlane(x, 63));
}

// ---------------- FPS body: symmetric waves, keys-only LDS round (R8/R10) --------
template <int NPTS, int NSAMP>
__device__ void fps_body(const float* __restrict__ coords, int b,
                         int* __restrict__ out_idx, float* __restrict__ out_pos,
                         char* smem_raw) {
  constexpr int PT = NPTS / 256;
  float* sx = (float*)smem_raw;                 // [NPTS]
  float* sy = sx + NPTS;                        // [NPTS]
  float* sz = sy + NPTS;                        // [NPTS]
  uint64_t* swk = (uint64_t*)(sz + NPTS);       // [2][4] keys
  const float* pos = coords + (size_t)b * NPTS * 3;
  const int tid = (int)threadIdx.x;
  const int lane = LANE, wid = WID;

  __builtin_amdgcn_s_setprio(3);  // FPS is the serial critical path

  float px[PT], py[PT], pz[PT], dd[PT];
  const int i0 = tid * PT;
#pragma unroll
  for (int k = 0; k < PT; ++k) {
    px[k] = pos[(i0 + k) * 3 + 0];
    py[k] = pos[(i0 + k) * 3 + 1];
    pz[k] = pos[(i0 + k) * 3 + 2];
    sx[i0 + k] = px[k]; sy[i0 + k] = py[k]; sz[i0 + k] = pz[k];
    dd[k] = __builtin_inff();
  }
  float fx = pos[0], fy = pos[1], fz = pos[2];
  if (tid == 0) {
    out_idx[(size_t)b * NSAMP] = 0;
    if (out_pos) {
      out_pos[(size_t)b * NSAMP * 3 + 0] = fx;
      out_pos[(size_t)b * NSAMP * 3 + 1] = fy;
      out_pos[(size_t)b * NSAMP * 3 + 2] = fz;
    }
  }
  __syncthreads();

  for (int s = 1; s < NSAMP; ++s) {
    float lv = -__builtin_inff();
    int li = 0;
#pragma unroll
    for (int k = 0; k < PT; ++k) {
      float d = exact_d2(px[k], py[k], pz[k], fx, fy, fz);
      float nd = fminf(dd[k], d);
      dd[k] = nd;
      bool gt = nd > lv;  // strict >: first k within thread wins ties
      lv = gt ? nd : lv;
      li = gt ? k : li;
    }
    const float wv = wave_max_dpp(lv);
    const uint64_t mball = __ballot(lv == wv);
    const int wl = (int)__ffsll((unsigned long long)mball) - 1;  // lowest lane
    const int par = s & 1;
    if (lane == wl) {
      swk[par * 4 + wid] =
          ((uint64_t)__float_as_uint(wv) << 32) | (unsigned)(NPTS - 1 - (i0 + li));
    }
    lds_barrier();  // key visible; vmcnt NOT drained
    const uint64_t* kp = swk + par * 4;
    const uint64_t ka = kp[0], kb = kp[1], kc = kp[2], kd = kp[3];
    const uint64_t k01 = kb > ka ? kb : ka;
    const uint64_t k23 = kd > kc ? kd : kc;
    const uint64_t kfin = k23 > k01 ? k23 : k01;
    const int widx = (NPTS - 1) - (int)(unsigned)(kfin & 0xFFFFFFFFu);
    fx = sx[widx]; fy = sy[widx]; fz = sz[widx];  // broadcast reads, bit-exact copies
    if (tid == 0) {
      out_idx[(size_t)b * NSAMP + s] = widx;
      if (out_pos) {
        out_pos[((size_t)b * NSAMP + s) * 3 + 0] = fx;
        out_pos[((size_t)b * NSAMP + s) * 3 + 1] = fy;
        out_pos[((size_t)b * NSAMP + s) * 3 + 2] = fz;
      }
    }
  }
}

// ---- exact neighbor selection: in-radius candidates, 64 nearest (d, then j) ----
// (R10-proven body; only change: bsearch range clipped to [0, bits(r2)] -- exact
// since the 64th-smallest distance is always < r2.)
template <int NPTS, int CAP>
__device__ __forceinline__ int select_neighbors(const float* __restrict__ bpos,
                                                float qx, float qy, float qz, float r2,
                                                char* wmem, unsigned* jl) {
  constexpr int SLOTS = CAP / 64;
  const int lane = LANE;
  uint64_t* list = (uint64_t*)wmem;
  const uint64_t ltmask = (1ull << lane) - 1ull;

  unsigned cnt = 0;
  for (int base = 0; base < NPTS; base += 64) {
    int j = base + lane;
    float d = exact_d2(bpos[j * 3], bpos[j * 3 + 1], bpos[j * 3 + 2], qx, qy, qz);
    bool pred = d < r2;
    uint64_t mask = __ballot(pred);
    if (pred) {
      unsigned p = cnt + (unsigned)__popcll(mask & ltmask);
      if (p < CAP) list[p] = ((uint64_t)__float_as_uint(d) << 32) | (unsigned)j;
    }
    cnt += (unsigned)__popcll(mask);
  }
  if (cnt > CAP) cnt = CAP;
  lds_fence();

  int m;
  if (cnt <= 64) {
    m = (int)cnt;
    jl[lane] = (lane < m) ? (unsigned)list[lane] : 0u;
  } else {
    m = 64;
    uint64_t e[SLOTS];
#pragma unroll
    for (int si = 0; si < SLOTS; ++si) {
      int p = lane + 64 * si;
      e[si] = (p < (int)cnt) ? list[p] : ~0ull;
    }
    // binary search for d* = 64th smallest distance bit-pattern
    unsigned lo = 0, hi = __float_as_uint(r2);
    while (lo < hi) {
      unsigned mid = (lo + hi) >> 1;
      unsigned c = 0;
#pragma unroll
      for (int si = 0; si < SLOTS; ++si)
        c += (unsigned)__popcll(__ballot((unsigned)(e[si] >> 32) <= mid));
      if (c >= 64u) hi = mid; else lo = mid + 1;
    }
    const unsigned dstar = lo;
    unsigned nlt = 0, nt = 0;
#pragma unroll
    for (int si = 0; si < SLOTS; ++si) {
      unsigned hb = (unsigned)(e[si] >> 32);
      nlt += (unsigned)__popcll(__ballot(hb < dstar));
      nt += (unsigned)__popcll(__ballot(hb == dstar));
    }
    const unsigned need = 64u - nlt;
    unsigned jsel = 0xFFFFFFFFu;
    if (nt != need) {  // distance tie at the cut -> keep `need` smallest j
      unsigned jlo = 0, jhi = (unsigned)NPTS - 1;
      while (jlo < jhi) {
        unsigned jmid = (jlo + jhi) >> 1;
        unsigned c = 0;
#pragma unroll
        for (int si = 0; si < SLOTS; ++si)
          c += (unsigned)__popcll(__ballot(
              ((unsigned)(e[si] >> 32) == dstar) && ((unsigned)e[si] <= jmid)));
        if (c >= need) jhi = jmid; else jlo = jmid + 1;
      }
      jsel = jlo;
    }
    unsigned c2 = 0;
#pragma unroll
    for (int si = 0; si < SLOTS; ++si) {
      unsigned hb = (unsigned)(e[si] >> 32), jj = (unsigned)e[si];
      bool p = (hb < dstar) || ((hb == dstar) && (jj <= jsel));
      uint64_t mask = __ballot(p);
      if (p) jl[c2 + (unsigned)__popcll(mask & ltmask)] = jj;
      c2 += (unsigned)__popcll(mask);
    }
  }
  lds_fence();
  return m;
}

// ---------------- conv1: H=64, lane = neighbor, y1[64] in regs ----------------
__device__ void conv1_body(const float* __restrict__ pos, const float* __restrict__ feats,
                           const float* __restrict__ w1, const float* __restrict__ b1,
                           const float* __restrict__ w2t, const float* __restrict__ b2,
                           float* __restrict__ out, int qid, char* wmem) {
  const int lane = LANE;
  const int b = qid >> 12, qi = qid & 4095;
  const float* bpos = pos + (size_t)b * 4096 * 3;
  const float qx = bpos[qi * 3 + 0], qy = bpos[qi * 3 + 1], qz = bpos[qi * 3 + 2];
  unsigned* jl = (unsigned*)(wmem + 8320);
  const int m = select_neighbors<4096, 512>(bpos, qx, qy, qz, 0.04f, wmem, jl);

  const bool valid = lane < m;
  const int j = valid ? (int)jl[lane] : 0;
  const float rx = bpos[j * 3 + 0] - qx;
  const float ry = bpos[j * 3 + 1] - qy;
  const float rz = bpos[j * 3 + 2] - qz;
  const float* xr = feats + ((size_t)b * 4096 + j) * 6;
  const float x0 = xr[0], x1 = xr[1], x2 = xr[2], x3 = xr[3], x4 = xr[4], x5 = xr[5];
  const float* w1r = w1 + 6 * 64;

  float y1[64];
#pragma unroll
  for (int f = 0; f < 64; ++f) {
    float a = b1[f];
    a = fmaf(x0, w1[0 * 64 + f], a);
    a = fmaf(x1, w1[1 * 64 + f], a);
    a = fmaf(x2, w1[2 * 64 + f], a);
    a = fmaf(x3, w1[3 * 64 + f], a);
    a = fmaf(x4, w1[4 * 64 + f], a);
    a = fmaf(x5, w1[5 * 64 + f], a);
    a = fmaf(rx, w1r[0 * 64 + f], a);
    a = fmaf(ry, w1r[1 * 64 + f], a);
    a = fmaf(rz, w1r[2 * 64 + f], a);
    y1[f] = fmaxf(a, 0.0f);
  }

  float* stg = (float*)wmem;  // [32][65], reuses candidate area
  float* orow = out + (size_t)qid * 64;
  const float NEG = -__builtin_inff();
#pragma unroll 1
  for (int cst = 0; cst < 64; cst += 32) {
    lds_fence();
#pragma unroll 1
    for (int g = 0; g < 32; ++g) {
      const float* wrow = w2t + (size_t)(cst + g) * 64;  // uniform -> s_load
      float a0 = 0.f, a1 = 0.f, a2 = 0.f, a3 = 0.f;
#pragma unroll
      for (int f = 0; f < 64; f += 4) {
        a0 = fmaf(y1[f], wrow[f], a0);
        a1 = fmaf(y1[f + 1], wrow[f + 1], a1);
        a2 = fmaf(y1[f + 2], wrow[f + 2], a2);
        a3 = fmaf(y1[f + 3], wrow[f + 3], a3);
      }
      float acc = b2[cst + g] + ((a0 + a1) + (a2 + a3));
      stg[g * 65 + lane] = valid ? acc : NEG;
    }
    lds_fence();
    const int r = lane & 31, jb = lane & 32;
    float mx = NEG;
#pragma unroll
    for (int t = 0; t < 32; ++t) mx = fmaxf(mx, stg[r * 65 + jb + t]);
    mx = fmaxf(mx, __shfl_xor(mx, 32));
    if (lane < 32) orow[cst + lane] = mx;
  }
}

// ------- conv2: H=128, TWO waves per query (wave-uniform feature half) -------
// Selection is computed ONCE per query by the half-0 wave (both waves previously
// ran the identical 2048-pt scan + bsearch); jl[64] + m are shared through the
// pair's LDS (jl at pairmem+8320 -- disjoint from the 8192B candidate list and
// from stgA's 8320B staging area), handed over by one block-wide barrier.
__device__ void conv2_body(const float* __restrict__ pos, const float* __restrict__ u,
                           const float* __restrict__ w1r, const float* __restrict__ w2t,
                           const float* __restrict__ b2, float* __restrict__ out,
                           int qid, int half, char* wmem, char* pairmem) {
  const int lane = LANE;
  const int b = qid >> 11, qi = qid & 2047;
  const float* bpos = pos + (size_t)b * 2048 * 3;
  const float qx = bpos[qi * 3 + 0], qy = bpos[qi * 3 + 1], qz = bpos[qi * 3 + 2];
  unsigned* jl = (unsigned*)(pairmem + 8320);
  int* mp = (int*)(pairmem + 8576);
  if (half == 0) {
    const int m0 = select_neighbors<2048, 1024>(bpos, qx, qy, qz, 0.16f, pairmem, jl);
    if (lane == 0) *mp = m0;
  }
  __syncthreads();  // jl + m visible to both halves (uniform barrier)
  const int m = *mp;
  const int fh = half * 64;

  const bool valid = lane < m;
  const int j = valid ? (int)jl[lane] : 0;
  const float rx = bpos[j * 3 + 0] - qx;
  const float ry = bpos[j * 3 + 1] - qy;
  const float rz = bpos[j * 3 + 2] - qz;
  const float* urow = u + ((size_t)b * 2048 + j) * 128 + fh;

  float y1[64];
#pragma unroll
  for (int t = 0; t < 64; t += 4) {
    float4 v = *reinterpret_cast<const float4*>(urow + t);
    y1[t] = v.x; y1[t + 1] = v.y; y1[t + 2] = v.z; y1[t + 3] = v.w;
  }
#pragma unroll
  for (int t = 0; t < 64; ++t) {
    float a = fmaf(rx, w1r[0 * 128 + fh + t], y1[t]);
    a = fmaf(ry, w1r[1 * 128 + fh + t], a);
    a = fmaf(rz, w1r[2 * 128 + fh + t], a);
    y1[t] = fmaxf(a, 0.0f);
  }

  float* stgA = (float*)pairmem;           // half-0 wave's [32][65]
  float* stgB = (float*)(pairmem + 8704);  // half-1 wave's [32][65]
  float* stg_own = half ? stgB : stgA;
  float* orow = out + (size_t)qid * 128;
  const float NEG = -__builtin_inff();
#pragma unroll 1
  for (int cst = 0; cst < 128; cst += 32) {
#pragma unroll 1
    for (int g = 0; g < 32; ++g) {
      const float* wrow = w2t + (size_t)(cst + g) * 128 + fh;  // uniform -> s_load
      float a0 = 0.f, a1 = 0.f, a2 = 0.f, a3 = 0.f;
#pragma unroll
      for (int t = 0; t < 64; t += 4) {
        a0 = fmaf(y1[t], wrow[t], a0);
        a1 = fmaf(y1[t + 1], wrow[t + 1], a1);
        a2 = fmaf(y1[t + 2], wrow[t + 2], a2);
        a3 = fmaf(y1[t + 3], wrow[t + 3], a3);
      }
      float pc = (a0 + a1) + (a2 + a3);
      stg_own[g * 65 + lane] = valid ? pc : (half ? 0.0f : NEG);
    }
    __syncthreads();
    if (half == 0) {
      const int r = lane & 31, jb = (lane >> 5) * 32;
      float mx = NEG;
#pragma unroll
      for (int t = 0; t < 32; ++t)
        mx = fmaxf(mx, stgA[r * 65 + jb + t] + stgB[r * 65 + jb + t]);
      mx = fmaxf(mx, __shfl_xor(mx, 32));
      if (lane < 32) orow[cst + lane] = mx + b2[cst + lane];
    }
    __syncthreads();
  }
}

// ---------------- fused stage kernels: blocks 0..7 = FPS, rest = conv ----------------
__global__ __launch_bounds__(256, 2) void stage1_kernel(
    const float* __restrict__ coords, const float* __restrict__ feats,
    const float* __restrict__ w1, const float* __restrict__ b1,
    const float* __restrict__ w2t, const float* __restrict__ b2,
    float* __restrict__ out, int* __restrict__ fps_idx, float* __restrict__ fps_pos) {
  __shared__ __align__(16) char smem[49216];  // fps: 48KB table + keys; conv: 4 x 9088
  if (blockIdx.x < 8) {
    fps_body<4096, 2048>(coords, (int)blockIdx.x, fps_idx, fps_pos, smem);
  } else {
    int qid = __builtin_amdgcn_readfirstlane(((int)blockIdx.x - 8) * 4 + WID);
    conv1_body(coords, feats, w1, b1, w2t, b2, out, qid, smem + WID * 9088);
  }
}

// (256,2): VGPR cap 128 -- conv2 needs ~80; (.,4) would cap at 64 and spill (R12).
__global__ __launch_bounds__(256, 2) void stage2_kernel(
    const float* __restrict__ p1, const float* __restrict__ u2,
    const float* __restrict__ w1r, const float* __restrict__ w2t,
    const float* __restrict__ b2, float* __restrict__ out,
    int* __restrict__ fps_idx) {
  __shared__ __align__(16) char smem[34816];  // fps: 24KB+keys; conv: 4 x 8704
  if (blockIdx.x < 8) {
    fps_body<2048, 512>(p1, (int)blockIdx.x, fps_idx, nullptr, smem);
  } else {
    const int wid = WID;
    const int half = __builtin_amdgcn_readfirstlane(wid & 1);
    const int qid =
        __builtin_amdgcn_readfirstlane(((int)blockIdx.x - 8) * 2 + (wid >> 1));
    conv2_body(p1, u2, w1r, w2t, b2, out, qid, half, smem + wid * 8704,
               smem + (wid & ~1) * 8704);
  }
}

// ------- u2 = b1b + h1[i1] @ W1b_feat (layer-1 factoring for stage 2) -------
__global__ __launch_bounds__(128) void u2_kernel(const float* __restrict__ h1,
                                                 const int* __restrict__ i1,
                                                 const float* __restrict__ w1,
                                                 const float* __restrict__ b1,
                                                 float* __restrict__ u2) {
  int row = blockIdx.x;  // 16384
  int f = (int)threadIdx.x;
  int b = row >> 11;
  int src = i1[row];
  const float* x = h1 + ((size_t)b * 4096 + src) * 64;
  float acc = b1[f];
#pragma unroll
  for (int k = 0; k < 64; ++k) acc = fmaf(x[k], w1[k * 128 + f], acc);
  u2[(size_t)row * 128 + f] = acc;
}

__global__ __launch_bounds__(256) void transpose_kernel(const float* __restrict__ w2a,
                                                        const float* __restrict__ w2b,
                                                        float* __restrict__ w2ta,
                                                        float* __restrict__ w2tb) {
  int gtid = blockIdx.x * 256 + (int)threadIdx.x;
  int stride = gridDim.x * 256;
  for (int t = gtid; t < 64 * 64; t += stride) w2ta[(t & 63) * 64 + (t >> 6)] = w2a[t];
  for (int t = gtid; t < 128 * 128; t += stride) w2tb[(t & 127) * 128 + (t >> 7)] = w2b[t];
}

// ---------------- global max pool over i2 + final linear ----------------
__global__ __launch_bounds__(512) void pool_linear_kernel(
    const float* __restrict__ h2, const int* __restrict__ i2,
    const float* __restrict__ wl, const float* __restrict__ bl,
    float* __restrict__ out) {
  int b = blockIdx.x;
  int c = (int)threadIdx.x >> 7;
  int f = (int)threadIdx.x & 127;
  __shared__ float part[4][128];
  __shared__ float feat[128];
  float mx = -__builtin_inff();
  const int* idx = i2 + b * 512;
  for (int s = c * 128; s < c * 128 + 128; ++s) {
    int j = idx[s];
    mx = fmaxf(mx, h2[((size_t)b * 2048 + j) * 128 + f]);
  }
  part[c][f] = mx;
  __syncthreads();
  if (c == 0) {
    feat[f] = fmaxf(fmaxf(part[0][f], part[1][f]), fmaxf(part[2][f], part[3][f]));
  }
  __syncthreads();
  if (c == 0) {
    float acc = bl[f];
#pragma unroll
    for (int k = 0; k < 128; ++k) acc = fmaf(feat[k], wl[k * 128 + f], acc);
    out[b * 128 + f] = acc;
  }
}

extern "C" void kernel_launch(void* const* d_in, const int* in_sizes, int n_in,
                              void* d_out, int out_size, void* d_ws, size_t ws_size,
                              hipStream_t stream) {
  const float* feats = (const float*)d_in[0];   // [8,4096,6]
  const float* coords = (const float*)d_in[1];  // [8,4096,3]
  const float* W1a = (const float*)d_in[2];     // [9,64]
  const float* b1a = (const float*)d_in[3];
  const float* W2a = (const float*)d_in[4];     // [64,64]
  const float* b2a = (const float*)d_in[5];
  const float* W1b = (const float*)d_in[6];     // [67,128]
  const float* b1b = (const float*)d_in[7];
  const float* W2b = (const float*)d_in[8];     // [128,128]
  const float* b2b = (const float*)d_in[9];
  const float* Wl = (const float*)d_in[10];     // [128,128]
  const float* bl = (const float*)d_in[11];

  float* ws = (float*)d_ws;
  float* W2TA = ws;                  // 4096
  float* W2TB = W2TA + 4096;         // 16384
  float* H1 = W2TB + 16384;          // 8*4096*64  = 2097152
  float* U2 = H1 + 2097152;          // 8*2048*128 = 2097152
  float* H2 = U2 + 2097152;          // 8*2048*128 = 2097152
  float* P1 = H2 + 2097152;          // 8*2048*3   = 49152
  int* I1 = (int*)(P1 + 49152);      // 8*2048
  int* I2 = I1 + 16384;              // 8*512

  transpose_kernel<<<80, 256, 0, stream>>>(W2a, W2b, W2TA, W2TB);
  // stage 1: fps1 (blocks 0-7) || conv1 (8192 blocks x 4 queries)
  stage1_kernel<<<8 + 8192, 256, 0, stream>>>(coords, feats, W1a, b1a, W2TA, b2a, H1,
                                              I1, P1);
  u2_kernel<<<16384, 128, 0, stream>>>(H1, I1, W1b, b1b, U2);
  // stage 2: fps2 (blocks 0-7) || conv2 (8192 blocks x 2 queries x 2 waves)
  stage2_kernel<<<8 + 8192, 256, 0, stream>>>(P1, U2, W1b + 64 * 128, W2TB, b2b, H2, I2);
  pool_linear_kernel<<<8, 512, 0, stream>>>(H2, I2, Wl, bl, (float*)d_out);
}

// Round 15
// 1566.742 us; speedup vs baseline: 1.9329x; 1.4610x over previous
//
#include <hip/hip_runtime.h>
#include <stdint.h>

#define LANE ((int)(threadIdx.x & 63))
#define WID  ((int)(threadIdx.x >> 6))

typedef short bf16x8 __attribute__((ext_vector_type(8)));
typedef float f32x4 __attribute__((ext_vector_type(4)));

__device__ __forceinline__ float exact_d2(float ax, float ay, float az,
                                          float bx, float by, float bz) {
  float dx = ax - bx, dy = ay - by, dz = az - bz;
  return __fadd_rn(__fadd_rn(__fmul_rn(dx, dx), __fmul_rn(dy, dy)), __fmul_rn(dz, dz));
}

__device__ __forceinline__ void lds_fence() {
  asm volatile("s_waitcnt lgkmcnt(0)" ::: "memory");
}

// Barrier that does NOT drain vmcnt: LDS-visibility fence + raw s_barrier.
__device__ __forceinline__ void lds_barrier() {
  asm volatile("s_waitcnt lgkmcnt(0)" ::: "memory");
  __builtin_amdgcn_s_barrier();
  asm volatile("" ::: "memory");
}

__device__ __host__ __forceinline__ unsigned short f2bf(float f) {
  union { float f; unsigned u; } v;
  v.f = f;
  unsigned r = v.u + 0x7FFFu + ((v.u >> 16) & 1u);  // RNE (finite inputs)
  return (unsigned short)(r >> 16);
}

// Wave-wide max via DPP. ROW_SHR 1/2/4/8 accumulates row maxima into lanes
// 15/31/47/63; row_bcast15 (rows 1,3) then row_bcast31 (rows 2,3) fold rows;
// lane 63 holds the full wave max. (R7-verified.)
__device__ __forceinline__ float wave_max_dpp(float v) {
  const int NI = 0xff800000;  // -inf bits: identity
  int x = __float_as_int(v);
  x = __float_as_int(fmaxf(__int_as_float(x),
      __int_as_float(__builtin_amdgcn_update_dpp(NI, x, 0x111, 0xf, 0xf, false))));
  x = __float_as_int(fmaxf(__int_as_float(x),
      __int_as_float(__builtin_amdgcn_update_dpp(NI, x, 0x112, 0xf, 0xf, false))));
  x = __float_as_int(fmaxf(__int_as_float(x),
      __int_as_float(__builtin_amdgcn_update_dpp(NI, x, 0x114, 0xf, 0xf, false))));
  x = __float_as_int(fmaxf(__int_as_float(x),
      __int_as_float(__builtin_amdgcn_update_dpp(NI, x, 0x118, 0xf, 0xf, false))));
  x = __float_as_int(fmaxf(__int_as_float(x),
      __int_as_float(__builtin_amdgcn_update_dpp(NI, x, 0x142, 0xa, 0xf, false))));
  x = __float_as_int(fmaxf(__int_as_float(x),
      __int_as_float(__builtin_amdgcn_update_dpp(NI, x, 0x143, 0xc, 0xf, false))));
  return __int_as_float(__builtin_amdgcn_readlane(x, 63));
}

// ---------------- FPS body: symmetric waves, keys-only LDS round (R8/R10) --------
template <int NPTS, int NSAMP>
__device__ void fps_body(const float* __restrict__ coords, int b,
                         int* __restrict__ out_idx, float* __restrict__ out_pos,
                         char* smem_raw) {
  constexpr int PT = NPTS / 256;
  float* sx = (float*)smem_raw;                 // [NPTS]
  float* sy = sx + NPTS;                        // [NPTS]
  float* sz = sy + NPTS;                        // [NPTS]
  uint64_t* swk = (uint64_t*)(sz + NPTS);       // [2][4] keys
  const float* pos = coords + (size_t)b * NPTS * 3;
  const int tid = (int)threadIdx.x;
  const int lane = LANE, wid = WID;

  __builtin_amdgcn_s_setprio(3);  // FPS is the serial critical path

  float px[PT], py[PT], pz[PT], dd[PT];
  const int i0 = tid * PT;
#pragma unroll
  for (int k = 0; k < PT; ++k) {
    px[k] = pos[(i0 + k) * 3 + 0];
    py[k] = pos[(i0 + k) * 3 + 1];
    pz[k] = pos[(i0 + k) * 3 + 2];
    sx[i0 + k] = px[k]; sy[i0 + k] = py[k]; sz[i0 + k] = pz[k];
    dd[k] = __builtin_inff();
  }
  float fx = pos[0], fy = pos[1], fz = pos[2];
  if (tid == 0) {
    out_idx[(size_t)b * NSAMP] = 0;
    if (out_pos) {
      out_pos[(size_t)b * NSAMP * 3 + 0] = fx;
      out_pos[(size_t)b * NSAMP * 3 + 1] = fy;
      out_pos[(size_t)b * NSAMP * 3 + 2] = fz;
    }
  }
  __syncthreads();

  for (int s = 1; s < NSAMP; ++s) {
    float lv = -__builtin_inff();
    int li = 0;
#pragma unroll
    for (int k = 0; k < PT; ++k) {
      float d = exact_d2(px[k], py[k], pz[k], fx, fy, fz);
      float nd = fminf(dd[k], d);
      dd[k] = nd;
      bool gt = nd > lv;  // strict >: first k within thread wins ties
      lv = gt ? nd : lv;
      li = gt ? k : li;
    }
    const float wv = wave_max_dpp(lv);
    const uint64_t mball = __ballot(lv == wv);
    const int wl = (int)__ffsll((unsigned long long)mball) - 1;  // lowest lane
    const int par = s & 1;
    if (lane == wl) {
      swk[par * 4 + wid] =
          ((uint64_t)__float_as_uint(wv) << 32) | (unsigned)(NPTS - 1 - (i0 + li));
    }
    lds_barrier();  // key visible; vmcnt NOT drained
    const uint64_t* kp = swk + par * 4;
    const uint64_t ka = kp[0], kb = kp[1], kc = kp[2], kd = kp[3];
    const uint64_t k01 = kb > ka ? kb : ka;
    const uint64_t k23 = kd > kc ? kd : kc;
    const uint64_t kfin = k23 > k01 ? k23 : k01;
    const int widx = (NPTS - 1) - (int)(unsigned)(kfin & 0xFFFFFFFFu);
    fx = sx[widx]; fy = sy[widx]; fz = sz[widx];  // broadcast reads, bit-exact copies
    if (tid == 0) {
      out_idx[(size_t)b * NSAMP + s] = widx;
      if (out_pos) {
        out_pos[((size_t)b * NSAMP + s) * 3 + 0] = fx;
        out_pos[((size_t)b * NSAMP + s) * 3 + 1] = fy;
        out_pos[((size_t)b * NSAMP + s) * 3 + 2] = fz;
      }
    }
  }
}

// ---- exact neighbor selection: in-radius candidates, 64 nearest (d, then j) ----
template <int NPTS, int CAP>
__device__ __forceinline__ int select_neighbors(const float* __restrict__ bpos,
                                                float qx, float qy, float qz, float r2,
                                                char* wmem, unsigned* jl) {
  constexpr int SLOTS = CAP / 64;
  const int lane = LANE;
  uint64_t* list = (uint64_t*)wmem;
  const uint64_t ltmask = (1ull << lane) - 1ull;

  unsigned cnt = 0;
  for (int base = 0; base < NPTS; base += 64) {
    int j = base + lane;
    float d = exact_d2(bpos[j * 3], bpos[j * 3 + 1], bpos[j * 3 + 2], qx, qy, qz);
    bool pred = d < r2;
    uint64_t mask = __ballot(pred);
    if (pred) {
      unsigned p = cnt + (unsigned)__popcll(mask & ltmask);
      if (p < CAP) list[p] = ((uint64_t)__float_as_uint(d) << 32) | (unsigned)j;
    }
    cnt += (unsigned)__popcll(mask);
  }
  if (cnt > CAP) cnt = CAP;
  lds_fence();

  int m;
  if (cnt <= 64) {
    m = (int)cnt;
    jl[lane] = (lane < m) ? (unsigned)list[lane] : 0u;
  } else {
    m = 64;
    uint64_t e[SLOTS];
#pragma unroll
    for (int si = 0; si < SLOTS; ++si) {
      int p = lane + 64 * si;
      e[si] = (p < (int)cnt) ? list[p] : ~0ull;
    }
    // binary search for d* = 64th smallest distance bit-pattern, range [0, bits(r2)]
    unsigned lo = 0, hi = __float_as_uint(r2);
    while (lo < hi) {
      unsigned mid = (lo + hi) >> 1;
      unsigned c = 0;
#pragma unroll
      for (int si = 0; si < SLOTS; ++si)
        c += (unsigned)__popcll(__ballot((unsigned)(e[si] >> 32) <= mid));
      if (c >= 64u) hi = mid; else lo = mid + 1;
    }
    const unsigned dstar = lo;
    unsigned nlt = 0, nt = 0;
#pragma unroll
    for (int si = 0; si < SLOTS; ++si) {
      unsigned hb = (unsigned)(e[si] >> 32);
      nlt += (unsigned)__popcll(__ballot(hb < dstar));
      nt += (unsigned)__popcll(__ballot(hb == dstar));
    }
    const unsigned need = 64u - nlt;
    unsigned jsel = 0xFFFFFFFFu;
    if (nt != need) {  // distance tie at the cut -> keep `need` smallest j
      unsigned jlo = 0, jhi = (unsigned)NPTS - 1;
      while (jlo < jhi) {
        unsigned jmid = (jlo + jhi) >> 1;
        unsigned c = 0;
#pragma unroll
        for (int si = 0; si < SLOTS; ++si)
          c += (unsigned)__popcll(__ballot(
              ((unsigned)(e[si] >> 32) == dstar) && ((unsigned)e[si] <= jmid)));
        if (c >= need) jhi = jmid; else jlo = jmid + 1;
      }
      jsel = jlo;
    }
    unsigned c2 = 0;
#pragma unroll
    for (int si = 0; si < SLOTS; ++si) {
      unsigned hb = (unsigned)(e[si] >> 32), jj = (unsigned)e[si];
      bool p = (hb < dstar) || ((hb == dstar) && (jj <= jsel));
      uint64_t mask = __ballot(p);
      if (p) jl[c2 + (unsigned)__popcll(mask & ltmask)] = jj;
      c2 += (unsigned)__popcll(mask);
    }
  }
  lds_fence();
  return m;
}

// ---------------- conv1: H=64, lane = neighbor, y1[64] in regs (fp32 exact) ------
__device__ void conv1_body(const float* __restrict__ pos, const float* __restrict__ feats,
                           const float* __restrict__ w1, const float* __restrict__ b1,
                           const float* __restrict__ w2t, const float* __restrict__ b2,
                           float* __restrict__ out, int qid, char* wmem) {
  const int lane = LANE;
  const int b = qid >> 12, qi = qid & 4095;
  const float* bpos = pos + (size_t)b * 4096 * 3;
  const float qx = bpos[qi * 3 + 0], qy = bpos[qi * 3 + 1], qz = bpos[qi * 3 + 2];
  unsigned* jl = (unsigned*)(wmem + 8320);
  const int m = select_neighbors<4096, 512>(bpos, qx, qy, qz, 0.04f, wmem, jl);

  const bool valid = lane < m;
  const int j = valid ? (int)jl[lane] : 0;
  const float rx = bpos[j * 3 + 0] - qx;
  const float ry = bpos[j * 3 + 1] - qy;
  const float rz = bpos[j * 3 + 2] - qz;
  const float* xr = feats + ((size_t)b * 4096 + j) * 6;
  const float x0 = xr[0], x1 = xr[1], x2 = xr[2], x3 = xr[3], x4 = xr[4], x5 = xr[5];
  const float* w1r = w1 + 6 * 64;

  float y1[64];
#pragma unroll
  for (int f = 0; f < 64; ++f) {
    float a = b1[f];
    a = fmaf(x0, w1[0 * 64 + f], a);
    a = fmaf(x1, w1[1 * 64 + f], a);
    a = fmaf(x2, w1[2 * 64 + f], a);
    a = fmaf(x3, w1[3 * 64 + f], a);
    a = fmaf(x4, w1[4 * 64 + f], a);
    a = fmaf(x5, w1[5 * 64 + f], a);
    a = fmaf(rx, w1r[0 * 64 + f], a);
    a = fmaf(ry, w1r[1 * 64 + f], a);
    a = fmaf(rz, w1r[2 * 64 + f], a);
    y1[f] = fmaxf(a, 0.0f);
  }

  float* stg = (float*)wmem;  // [32][65], reuses candidate area
  float* orow = out + (size_t)qid * 64;
  const float NEG = -__builtin_inff();
#pragma unroll 1
  for (int cst = 0; cst < 64; cst += 32) {
    lds_fence();
#pragma unroll 1
    for (int g = 0; g < 32; ++g) {
      const float* wrow = w2t + (size_t)(cst + g) * 64;  // uniform -> s_load
      float a0 = 0.f, a1 = 0.f, a2 = 0.f, a3 = 0.f;
#pragma unroll
      for (int f = 0; f < 64; f += 4) {
        a0 = fmaf(y1[f], wrow[f], a0);
        a1 = fmaf(y1[f + 1], wrow[f + 1], a1);
        a2 = fmaf(y1[f + 2], wrow[f + 2], a2);
        a3 = fmaf(y1[f + 3], wrow[f + 3], a3);
      }
      float acc = b2[cst + g] + ((a0 + a1) + (a2 + a3));
      stg[g * 65 + lane] = valid ? acc : NEG;
    }
    lds_fence();
    const int r = lane & 31, jb = lane & 32;
    float mx = NEG;
#pragma unroll
    for (int t = 0; t < 32; ++t) mx = fmaxf(mx, stg[r * 65 + jb + t]);
    mx = fmaxf(mx, __shfl_xor(mx, 32));
    if (lane < 32) orow[cst + lane] = mx;
  }
}

// ------- conv2 via MFMA: Y[64n][128t](bf16,LDS) @ W2[128t][128g](bf16) -------
// 2 waves/query. Selection once (half-0), shared via LDS. Wave h computes y1
// fp32 for t-half [64h,64h+64) (lane = neighbor), stages Y bf16 with XOR swizzle
// (byte ^= (row&7)<<4). Then wave h computes output half g in [64h,64h+64):
// 4x4 C-tiles x 4 K-steps = 64 x mfma_f32_16x16x32_bf16. Rows >= m masked to
// -inf post-MFMA (C layout: col=lane&15, row=(lane>>4)*4+i), column max via
// 2 shfl_xor, +b2 after max (monotone-exact).
__device__ void conv2_body(const float* __restrict__ pos, const float* __restrict__ u,
                           const float* __restrict__ w1r,
                           const unsigned short* __restrict__ w2bh,
                           const float* __restrict__ b2, float* __restrict__ out,
                           int qid, int half, char* pairmem) {
  const int lane = LANE;
  const int b = qid >> 11, qi = qid & 2047;
  const float* bpos = pos + (size_t)b * 2048 * 3;
  const float qx = bpos[qi * 3 + 0], qy = bpos[qi * 3 + 1], qz = bpos[qi * 3 + 2];
  unsigned* jl = (unsigned*)(pairmem + 16384);
  int* mp = (int*)(pairmem + 16640);
  if (half == 0) {  // candidate list lives in the Y area (dead before Y written)
    const int m0 = select_neighbors<2048, 1024>(bpos, qx, qy, qz, 0.16f, pairmem, jl);
    if (lane == 0) *mp = m0;
  }
  __syncthreads();  // jl + m visible to both halves
  const int m = *mp;
  const int fh = half * 64;

  const bool valid = lane < m;
  const int j = valid ? (int)jl[lane] : 0;
  const float rx = bpos[j * 3 + 0] - qx;
  const float ry = bpos[j * 3 + 1] - qy;
  const float rz = bpos[j * 3 + 2] - qz;
  const float* urow = u + ((size_t)b * 2048 + j) * 128 + fh;

  float y1[64];
#pragma unroll
  for (int t = 0; t < 64; t += 4) {
    float4 v = *reinterpret_cast<const float4*>(urow + t);
    y1[t] = v.x; y1[t + 1] = v.y; y1[t + 2] = v.z; y1[t + 3] = v.w;
  }
#pragma unroll
  for (int t = 0; t < 64; ++t) {
    float a = fmaf(rx, w1r[0 * 128 + fh + t], y1[t]);
    a = fmaf(ry, w1r[1 * 128 + fh + t], a);
    a = fmaf(rz, w1r[2 * 128 + fh + t], a);
    y1[t] = fmaxf(a, 0.0f);
  }

  // ---- stage Y bf16: lane = row n, t-half fh..fh+63, swizzled 16B chunks ----
  {
    const unsigned base = (unsigned)lane * 256u + (unsigned)fh * 2u;
#pragma unroll
    for (int c = 0; c < 8; ++c) {
      unsigned uw0 = (unsigned)f2bf(y1[c * 8 + 0]) | ((unsigned)f2bf(y1[c * 8 + 1]) << 16);
      unsigned uw1 = (unsigned)f2bf(y1[c * 8 + 2]) | ((unsigned)f2bf(y1[c * 8 + 3]) << 16);
      unsigned uw2 = (unsigned)f2bf(y1[c * 8 + 4]) | ((unsigned)f2bf(y1[c * 8 + 5]) << 16);
      unsigned uw3 = (unsigned)f2bf(y1[c * 8 + 6]) | ((unsigned)f2bf(y1[c * 8 + 7]) << 16);
      unsigned addr = (base + (unsigned)c * 16u) ^ (((unsigned)lane & 7u) << 4);
      *reinterpret_cast<uint4*>(pairmem + addr) = make_uint4(uw0, uw1, uw2, uw3);
    }
  }
  __syncthreads();  // full Y[64][128] staged by both halves

  // ---- MFMA: Z-half = Y @ W2[:, fh..fh+63] ----
  f32x4 acc[4][4];
#pragma unroll
  for (int mi = 0; mi < 4; ++mi)
#pragma unroll
    for (int ni = 0; ni < 4; ++ni) acc[mi][ni] = (f32x4){0.f, 0.f, 0.f, 0.f};
  const int lrow = lane & 15, lk = lane >> 4;
#pragma unroll
  for (int ks = 0; ks < 4; ++ks) {
    bf16x8 bfr[4];
#pragma unroll
    for (int ni = 0; ni < 4; ++ni) {  // B[k][n] = W2T_bf16[g][t], 16B/lane, L2-hot
      const int g = fh + ni * 16 + lrow;
      const int t0 = ks * 32 + lk * 8;
      bfr[ni] = *reinterpret_cast<const bf16x8*>(w2bh + (size_t)g * 128 + t0);
    }
#pragma unroll
    for (int mi = 0; mi < 4; ++mi) {
      const unsigned row = (unsigned)(mi * 16 + lrow);
      unsigned addr = (row * 256u + (unsigned)(ks * 32 + lk * 8) * 2u) ^ ((row & 7u) << 4);
      bf16x8 afr = *reinterpret_cast<const bf16x8*>(pairmem + addr);
#pragma unroll
      for (int ni = 0; ni < 4; ++ni)
        acc[mi][ni] =
            __builtin_amdgcn_mfma_f32_16x16x32_bf16(afr, bfr[ni], acc[mi][ni], 0, 0, 0);
    }
  }

  // ---- masked column max over neighbor rows + bias + store ----
  const float NEG = -__builtin_inff();
  float mx0 = NEG, mx1 = NEG, mx2 = NEG, mx3 = NEG;
#pragma unroll
  for (int mi = 0; mi < 4; ++mi)
#pragma unroll
    for (int i = 0; i < 4; ++i) {
      const bool rv = (mi * 16 + lk * 4 + i) < m;
      mx0 = fmaxf(mx0, rv ? acc[mi][0][i] : NEG);
      mx1 = fmaxf(mx1, rv ? acc[mi][1][i] : NEG);
      mx2 = fmaxf(mx2, rv ? acc[mi][2][i] : NEG);
      mx3 = fmaxf(mx3, rv ? acc[mi][3][i] : NEG);
    }
  mx0 = fmaxf(mx0, __shfl_xor(mx0, 16)); mx0 = fmaxf(mx0, __shfl_xor(mx0, 32));
  mx1 = fmaxf(mx1, __shfl_xor(mx1, 16)); mx1 = fmaxf(mx1, __shfl_xor(mx1, 32));
  mx2 = fmaxf(mx2, __shfl_xor(mx2, 16)); mx2 = fmaxf(mx2, __shfl_xor(mx2, 32));
  mx3 = fmaxf(mx3, __shfl_xor(mx3, 16)); mx3 = fmaxf(mx3, __shfl_xor(mx3, 32));
  if (lane < 16) {
    float* orow = out + (size_t)qid * 128;
    orow[fh + 0 * 16 + lane] = mx0 + b2[fh + 0 * 16 + lane];
    orow[fh + 1 * 16 + lane] = mx1 + b2[fh + 1 * 16 + lane];
    orow[fh + 2 * 16 + lane] = mx2 + b2[fh + 2 * 16 + lane];
    orow[fh + 3 * 16 + lane] = mx3 + b2[fh + 3 * 16 + lane];
  }
}

// ---------------- fused stage kernels: blocks 0..7 = FPS, rest = conv ----------------
__global__ __launch_bounds__(256, 2) void stage1_kernel(
    const float* __restrict__ coords, const float* __restrict__ feats,
    const float* __restrict__ w1, const float* __restrict__ b1,
    const float* __restrict__ w2t, const float* __restrict__ b2,
    float* __restrict__ out, int* __restrict__ fps_idx, float* __restrict__ fps_pos) {
  __shared__ __align__(16) char smem[49216];  // fps: 48KB table + keys; conv: 4 x 9088
  if (blockIdx.x < 8) {
    fps_body<4096, 2048>(coords, (int)blockIdx.x, fps_idx, fps_pos, smem);
  } else {
    int qid = __builtin_amdgcn_readfirstlane(((int)blockIdx.x - 8) * 4 + WID);
    conv1_body(coords, feats, w1, b1, w2t, b2, out, qid, smem + WID * 9088);
  }
}

// (256,2): VGPR cap 128 -- MFMA conv2 needs ~100; (.,4) would cap at 64 (R12).
__global__ __launch_bounds__(256, 2) void stage2_kernel(
    const float* __restrict__ p1, const float* __restrict__ u2,
    const float* __restrict__ w1r, const unsigned short* __restrict__ w2bh,
    const float* __restrict__ b2, float* __restrict__ out,
    int* __restrict__ fps_idx) {
  __shared__ __align__(16) char smem[33792];  // fps: 24.7KB; conv: 2 x 16896
  if (blockIdx.x < 8) {
    fps_body<2048, 512>(p1, (int)blockIdx.x, fps_idx, nullptr, smem);
  } else {
    const int wid = WID;
    const int half = __builtin_amdgcn_readfirstlane(wid & 1);
    const int qid =
        __builtin_amdgcn_readfirstlane(((int)blockIdx.x - 8) * 2 + (wid >> 1));
    conv2_body(p1, u2, w1r, w2bh, b2, out, qid, half, smem + (wid >> 1) * 16896);
  }
}

// ------- u2 = b1b + h1[i1] @ W1b_feat (layer-1 factoring for stage 2) -------
__global__ __launch_bounds__(128) void u2_kernel(const float* __restrict__ h1,
                                                 const int* __restrict__ i1,
                                                 const float* __restrict__ w1,
                                                 const float* __restrict__ b1,
                                                 float* __restrict__ u2) {
  int row = blockIdx.x;  // 16384
  int f = (int)threadIdx.x;
  int b = row >> 11;
  int src = i1[row];
  const float* x = h1 + ((size_t)b * 4096 + src) * 64;
  float acc = b1[f];
#pragma unroll
  for (int k = 0; k < 64; ++k) acc = fmaf(x[k], w1[k * 128 + f], acc);
  u2[(size_t)row * 128 + f] = acc;
}

// W2TA fp32 (conv1) + W2b bf16 transpose [g][t] (conv2 MFMA B-operand).
__global__ __launch_bounds__(256) void transpose_kernel(const float* __restrict__ w2a,
                                                        const float* __restrict__ w2b,
                                                        float* __restrict__ w2ta,
                                                        unsigned short* __restrict__ w2bh) {
  int gtid = blockIdx.x * 256 + (int)threadIdx.x;
  int stride = gridDim.x * 256;
  for (int t = gtid; t < 64 * 64; t += stride) w2ta[(t & 63) * 64 + (t >> 6)] = w2a[t];
  for (int t = gtid; t < 128 * 128; t += stride)
    w2bh[(t & 127) * 128 + (t >> 7)] = f2bf(w2b[t]);
}

// ---------------- global max pool over i2 + final linear ----------------
__global__ __launch_bounds__(512) void pool_linear_kernel(
    const float* __restrict__ h2, const int* __restrict__ i2,
    const float* __restrict__ wl, const float* __restrict__ bl,
    float* __restrict__ out) {
  int b = blockIdx.x;
  int c = (int)threadIdx.x >> 7;
  int f = (int)threadIdx.x & 127;
  __shared__ float part[4][128];
  __shared__ float feat[128];
  float mx = -__builtin_inff();
  const int* idx = i2 + b * 512;
  for (int s = c * 128; s < c * 128 + 128; ++s) {
    int j = idx[s];
    mx = fmaxf(mx, h2[((size_t)b * 2048 + j) * 128 + f]);
  }
  part[c][f] = mx;
  __syncthreads();
  if (c == 0) {
    feat[f] = fmaxf(fmaxf(part[0][f], part[1][f]), fmaxf(part[2][f], part[3][f]));
  }
  __syncthreads();
  if (c == 0) {
    float acc = bl[f];
#pragma unroll
    for (int k = 0; k < 128; ++k) acc = fmaf(feat[k], wl[k * 128 + f], acc);
    out[b * 128 + f] = acc;
  }
}

extern "C" void kernel_launch(void* const* d_in, const int* in_sizes, int n_in,
                              void* d_out, int out_size, void* d_ws, size_t ws_size,
                              hipStream_t stream) {
  const float* feats = (const float*)d_in[0];   // [8,4096,6]
  const float* coords = (const float*)d_in[1];  // [8,4096,3]
  const float* W1a = (const float*)d_in[2];     // [9,64]
  const float* b1a = (const float*)d_in[3];
  const float* W2a = (const float*)d_in[4];     // [64,64]
  const float* b2a = (const float*)d_in[5];
  const float* W1b = (const float*)d_in[6];     // [67,128]
  const float* b1b = (const float*)d_in[7];
  const float* W2b = (const float*)d_in[8];     // [128,128]
  const float* b2b = (const float*)d_in[9];
  const float* Wl = (const float*)d_in[10];     // [128,128]
  const float* bl = (const float*)d_in[11];

  float* ws = (float*)d_ws;
  float* W2TA = ws;                            // 4096 floats
  unsigned short* W2BH = (unsigned short*)(W2TA + 4096);  // 16384 ushorts (8192 fl)
  float* H1 = W2TA + 4096 + 8192;              // 8*4096*64  = 2097152
  float* U2 = H1 + 2097152;                    // 8*2048*128 = 2097152
  float* H2 = U2 + 2097152;                    // 8*2048*128 = 2097152
  float* P1 = H2 + 2097152;                    // 8*2048*3   = 49152
  int* I1 = (int*)(P1 + 49152);                // 8*2048
  int* I2 = I1 + 16384;                        // 8*512

  transpose_kernel<<<80, 256, 0, stream>>>(W2a, W2b, W2TA, W2BH);
  // stage 1: fps1 (blocks 0-7) || conv1 (8192 blocks x 4 queries)
  stage1_kernel<<<8 + 8192, 256, 0, stream>>>(coords, feats, W1a, b1a, W2TA, b2a, H1,
                                              I1, P1);
  u2_kernel<<<16384, 128, 0, stream>>>(H1, I1, W1b, b1b, U2);
  // stage 2: fps2 (blocks 0-7) || conv2-MFMA (8192 blocks x 2 queries x 2 waves)
  stage2_kernel<<<8 + 8192, 256, 0, stream>>>(P1, U2, W1b + 64 * 128, W2BH, b2b, H2, I2);
  pool_linear_kernel<<<8, 512, 0, stream>>>(H2, I2, Wl, bl, (float*)d_out);
}